// Round 20
// baseline (82.580 us; speedup 1.0000x reference)
//
#include <hip/hip_runtime.h>
#include <hip/hip_bf16.h>

#define B_ 16
#define S_ 512
#define H_ 768
#define TS_ 20
#define IS_ 20
#define D_ 808
#define M_ 36
#define E_ 12
#define RNUM_ 97
#define D2_ 50
#define P_ (E_*E_)        // 144
#define NODES_ (M_+1)     // 37
#define NCOL_ (D2_*D_)    // 40400
#define MROWS_ (B_*E_)    // 192
#define KSTEPS_ 26
#define KPAD_ (KSTEPS_*32)  // 832
#define TC_ 8               // token chunks (64 tokens each)
#define ROWPAD_ 1040        // 1024B (2 k-rows x 128 cols fp32) + 16B pad
#define TILEB2_ (16*ROWPAD_) // 16640 B per K-step tile (32 k x 128 cols)

typedef __attribute__((ext_vector_type(8))) short bf16x8;
typedef __attribute__((ext_vector_type(4))) float f32x4;

__device__ inline unsigned short f2bf(float f) {
  union { float f; unsigned u; } v; v.f = f;
  unsigned r = v.u + 0x7FFFu + ((v.u >> 16) & 1u);
  return (unsigned short)(r >> 16);
}

__device__ inline unsigned pack2bf(float a, float b) {
  union { __hip_bfloat162 h; unsigned u; } p;
  p.h = __float22bfloat162_rn(make_float2(a, b));
  return p.u;
}

__device__ inline void gll16(const float* src, void* lds) {
  __builtin_amdgcn_global_load_lds(
      (const __attribute__((address_space(1))) unsigned int*)src,
      (__attribute__((address_space(3))) unsigned int*)lds, 16, 0, 0);
}

// ---------------- kernel 1: token-parallel fused pooling (partials) ----------
__global__ __launch_bounds__(256) void k_pool(
    const float* __restrict__ enc, const int* __restrict__ etype,
    const int* __restrict__ eidv, const int* __restrict__ midv,
    const float* __restrict__ tbl, const float* __restrict__ temb,
    const float* __restrict__ iemb, float* __restrict__ partial) {
  int tc = blockIdx.x;
  int b  = blockIdx.y;
  int t  = threadIdx.x;
  __shared__ int midS[S_];
  __shared__ int cntS[NODES_];
  __shared__ int tyC[64], ivC[64];
  __shared__ float tblS[E_][NODES_];
  __shared__ float wtab[E_][40];
  __shared__ float wclsS[E_];
  __shared__ float invTS[E_];

  for (int i = t; i < NODES_; i += 256) cntS[i] = 0;
  __syncthreads();
  for (int s = t; s < S_; s += 256) {
    int m = midv[b * S_ + s];
    midS[s] = m;
    atomicAdd(&cntS[m], 1);
  }
  if (t < 64) {
    int s = tc * 64 + t;
    tyC[t] = etype[b * S_ + s];
    ivC[t] = eidv[b * S_ + s];
  }
  for (int i = t; i < E_ * NODES_; i += 256) {
    int e = i / NODES_, n = i % NODES_;
    tblS[e][n] = tbl[(size_t)(b * (E_ + 1) + (e + 1)) * NODES_ + n];
  }
  __syncthreads();
  if (t < E_) {
    float s = 0.f;
    for (int n = 0; n < NODES_; ++n) s += tblS[t][n];
    invTS[t] = (s > 0.f) ? 1.0f / s : 1.0f;
    wclsS[t] = tblS[t][0] * invTS[t];
  }
  __syncthreads();
  for (int i = t; i < E_ * NODES_; i += 256) {
    int e = i / NODES_, n = i % NODES_;
    wtab[e][n] = (n >= 1 && cntS[n] > 0)
                     ? tblS[e][n] * invTS[e] / (float)cntS[n] : 0.0f;
  }
  __syncthreads();

  const float* encB = enc + (size_t)(b * S_) * H_;
  if (t < 192) {
    f32x4 acc[E_];
    if (tc == 0) {
      float4 c = *(const float4*)(encB + 4 * t);
      #pragma unroll
      for (int e = 0; e < E_; ++e) {
        float w = wclsS[e];
        acc[e] = (f32x4){w * c.x, w * c.y, w * c.z, w * c.w};
      }
    } else {
      #pragma unroll
      for (int e = 0; e < E_; ++e) acc[e] = (f32x4){0.f, 0.f, 0.f, 0.f};
    }
    #pragma unroll 4
    for (int s = 0; s < 64; ++s) {
      int m = midS[tc * 64 + s];
      float4 v = *(const float4*)(encB + (size_t)(tc * 64 + s) * H_ + 4 * t);
      #pragma unroll
      for (int e = 0; e < E_; ++e) {
        float w = wtab[e][m];
        acc[e][0] += w * v.x;
        acc[e][1] += w * v.y;
        acc[e][2] += w * v.z;
        acc[e][3] += w * v.w;
      }
    }
    float* prow = partial + (size_t)(tc * MROWS_ + b * E_) * D_;
    #pragma unroll
    for (int e = 0; e < E_; ++e)
      *(f32x4*)(prow + (size_t)e * D_ + 4 * t) = acc[e];
  } else if (t - 192 < TS_ + IS_) {
    int tt = t - 192;
    float acc[E_];
    #pragma unroll
    for (int e = 0; e < E_; ++e) acc[e] = 0.f;
    for (int s = 0; s < 64; ++s) {
      int m = midS[tc * 64 + s];
      float val = (tt < TS_) ? temb[tyC[s] * TS_ + tt]
                             : iemb[ivC[s] * IS_ + (tt - TS_)];
      #pragma unroll
      for (int e = 0; e < E_; ++e) acc[e] += wtab[e][m] * val;
    }
    float* prow = partial + (size_t)(tc * MROWS_ + b * E_) * D_;
    #pragma unroll
    for (int e = 0; e < E_; ++e) prow[(size_t)e * D_ + H_ + tt] = acc[e];
  }
}

// ---------------- kernel 1b: reduce partials -> bf16 pre-swizzled eswz -------
__global__ __launch_bounds__(256) void k_entred(
    const float* __restrict__ partial, short* __restrict__ eswz) {
  int row = blockIdx.x;   // 0..191
  int t = threadIdx.x;
  for (int d = t; d < D_; d += 256) {
    float s = 0.f;
    #pragma unroll
    for (int tc = 0; tc < TC_; ++tc)
      s += partial[((size_t)tc * MROWS_ + row) * D_ + d];
    eswz[((size_t)(d >> 3) * MROWS_ + row) * 8 + (d & 7)] = (short)f2bf(s);
  }
  if (t < KPAD_ - D_) {
    int d = D_ + t;
    eswz[((size_t)(d >> 3) * MROWS_ + row) * 8 + (d & 7)] = 0;
  }
}

// ---------------- kernel 2: Abf[192,40400] = Ent @ Wview (BN=128) ------------
// BM=192 BN=128 BK=32. W fp32 -> LDS via global_load_lds; one instr = 2 full
// k-rows (1024B contiguous). Layout byte(k,c) = (k>>1)*1040 + (k&1)*512 + c*4
// -> bank = (4*(k>>1)+c)%32: groups {0,2}/{1,3} alias = 2-way = free.
// Waves 2x2: 96 rows x 64 cols each. 3-buf, stage 2 ahead.
__global__ __launch_bounds__(256) void k_gemm(
    const float* __restrict__ Wf, const short* __restrict__ eswz,
    short* __restrict__ Abf) {
  __shared__ __align__(16) char Bs[3 * TILEB2_];   // 49920 B
  const int tid = threadIdx.x;
  const int lane = tid & 63;
  const int ln15 = lane & 15;
  const int g = (lane >> 4) & 3;
  const int wv = tid >> 6;
  const int wr = wv >> 1;          // 0..1: row half (96 rows)
  const int wc = wv & 1;           // 0..1: col half (64 cols)
  const int colBase = blockIdx.x * 128;

  f32x4 acc[6][4];
  #pragma unroll
  for (int i = 0; i < 6; ++i)
    #pragma unroll
    for (int j = 0; j < 4; ++j)
      acc[i][j] = (f32x4){0.f, 0.f, 0.f, 0.f};

  // stage tile t: 16 blocks of 1024B (2 k-rows x 128 cols); 4 instr/thread
  auto STAGE = [&](int t, int bufi) {
    #pragma unroll
    for (int r2 = 0; r2 < 4; ++r2) {
      int bi = r2 * 4 + wv;                      // 0..15 (wave-uniform)
      int kg = t * 32 + bi * 2 + (lane >> 5);    // per-lane k row
      if (kg > D_ - 1) kg = D_ - 1;              // tail killed by eswz zeros
      int cg = colBase + (lane & 31) * 4;
      if (cg > NCOL_ - 4) cg = NCOL_ - 4;        // last block clamp
      gll16(Wf + (size_t)kg * NCOL_ + cg, Bs + bufi * TILEB2_ + bi * ROWPAD_);
    }
  };

  STAGE(0, 0);
  STAGE(1, 1);
  __syncthreads();

  int rb = 0;
  for (int t = 0; t < KSTEPS_; ++t) {
    int sb = rb + 2; if (sb >= 3) sb -= 3;
    if (t + 2 < KSTEPS_) STAGE(t + 2, sb);
    const char* bb = Bs + rb * TILEB2_;
    // B fragments: 32 fp32 LDS reads (2-way banks = free), cvt to bf16
    bf16x8 bfr[4];
    #pragma unroll
    for (int nt = 0; nt < 4; ++nt) {
      float f[8];
      #pragma unroll
      for (int e = 0; e < 8; ++e) {
        int k = g * 8 + e;
        int col = wc * 64 + nt * 16 + ln15;
        f[e] = *(const float*)(bb + (k >> 1) * ROWPAD_ + (k & 1) * 512 + col * 4);
      }
      union { bf16x8 v; unsigned u[4]; } u;
      #pragma unroll
      for (int e2 = 0; e2 < 4; ++e2)
        u.u[e2] = pack2bf(f[2 * e2], f[2 * e2 + 1]);
      bfr[nt] = u.v;
    }
    // A fragments: 6 x dwordx4 from eswz (L2-resident)
    bf16x8 af[6];
    #pragma unroll
    for (int mt = 0; mt < 6; ++mt)
      af[mt] = *(const bf16x8*)&eswz[
          ((size_t)(t * 4 + g) * MROWS_ + wr * 96 + mt * 16 + ln15) * 8];
    #pragma unroll
    for (int mt = 0; mt < 6; ++mt)
      #pragma unroll
      for (int nt = 0; nt < 4; ++nt)
        acc[mt][nt] = __builtin_amdgcn_mfma_f32_16x16x32_bf16(
            af[mt], bfr[nt], acc[mt][nt], 0, 0, 0);
    __syncthreads();
    rb = (rb == 2) ? 0 : rb + 1;
  }

  // epilogue: C/D layout col = lane&15, row = g*4 + j; store bf16
  #pragma unroll
  for (int mt = 0; mt < 6; ++mt) {
    int row = wr * 96 + mt * 16 + g * 4;
    #pragma unroll
    for (int nt = 0; nt < 4; ++nt) {
      int col = colBase + wc * 64 + nt * 16 + ln15;
      if (col < NCOL_) {
        #pragma unroll
        for (int j = 0; j < 4; ++j)
          Abf[(size_t)(row + j) * NCOL_ + col] = (short)f2bf(acc[mt][nt][j]);
      }
    }
  }
}

// ---------------- kernel 3: z via MFMA — one wave per (b, r) ---------------
__global__ __launch_bounds__(64) void k_score_z(
    const short* __restrict__ Abf, const short* __restrict__ eswz,
    float* __restrict__ zbuf) {
  int w = blockIdx.x;            // 0..799
  int b = w / D2_;
  int r = w % D2_;
  int lane = threadIdx.x;
  int ln15 = lane & 15;
  int g = lane >> 4;
  int m = b * E_ + ln15;
  if (m > MROWS_ - 1) m = MROWS_ - 1;
  const short* ab = Abf + (size_t)m * NCOL_ + (size_t)r * D_ + g * 8;
  const short* bb = eswz + ((size_t)g * MROWS_ + m) * 8;
  f32x4 acc = (f32x4){0.f, 0.f, 0.f, 0.f};
  #pragma unroll
  for (int t = 0; t < KSTEPS_; ++t) {
    bf16x8 af = *(const bf16x8*)(ab + t * 32);
    bf16x8 bf = *(const bf16x8*)(bb + (size_t)t * 4 * MROWS_ * 8);
    acc = __builtin_amdgcn_mfma_f32_16x16x32_bf16(af, bf, acc, 0, 0, 0);
  }
  if (ln15 < E_ && g < 3) {
    #pragma unroll
    for (int jj = 0; jj < 4; ++jj)
      zbuf[(size_t)(b * E_ + g * 4 + jj) * (D2_ * E_) + r * E_ + ln15] = acc[jj];
  }
}

// ---------------- kernel 4: BN + R projection ------------------------------
__global__ __launch_bounds__(256) void k_out(
    const float* __restrict__ zbuf, const float* __restrict__ Rm,
    const float* __restrict__ gam, const float* __restrict__ bet,
    const float* __restrict__ mu, const float* __restrict__ var,
    float* __restrict__ out) {
  int blk = blockIdx.x;   // b*12+ke
  int t = threadIdx.x;
  __shared__ float zS[D2_ * E_];       // 600
  __shared__ float Rs[RNUM_ * D2_];    // 4850
  for (int i = t; i < D2_ * E_; i += 256) {
    int r = i / E_;
    float z = zbuf[(size_t)blk * (D2_ * E_) + i];
    zS[i] = (z - mu[r]) * rsqrtf(var[r] + 1e-5f) * gam[r] + bet[r];
  }
  for (int i = t; i < RNUM_ * D2_; i += 256) Rs[i] = Rm[i];
  __syncthreads();
  for (int o = t; o < E_ * RNUM_; o += 256) {
    int je = o / RNUM_;
    int k = o % RNUM_;
    float s = 0.f;
    #pragma unroll
    for (int r = 0; r < D2_; ++r) s += zS[r * E_ + je] * Rs[k * D2_ + r];
    out[(size_t)blk * (E_ * RNUM_) + o] = s;
  }
}

extern "C" void kernel_launch(void* const* d_in, const int* in_sizes, int n_in,
                              void* d_out, int out_size, void* d_ws, size_t ws_size,
                              hipStream_t stream) {
  const float* enc  = (const float*)d_in[0];
  const int*  etype = (const int*)d_in[1];
  const int*  eidv  = (const int*)d_in[2];
  const int*  midv  = (const int*)d_in[3];
  const float* tbl  = (const float*)d_in[4];
  const float* temb = (const float*)d_in[5];
  const float* iemb = (const float*)d_in[6];
  const float* W    = (const float*)d_in[7];
  const float* Rm   = (const float*)d_in[8];
  const float* gam  = (const float*)d_in[9];
  const float* bet  = (const float*)d_in[10];
  const float* mu   = (const float*)d_in[11];
  const float* var  = (const float*)d_in[12];

  // ws layout: zbuf | eswz | Abf | partial
  float* ws    = (float*)d_ws;
  float* zbuf  = ws;                                           // 115,200 f
  short* eswz  = (short*)(zbuf + (size_t)MROWS_ * D2_ * E_);   // 159,744 sh
  short* Abf   = eswz + (size_t)104 * MROWS_ * 8;              // 7,756,800 sh
  float* partial = (float*)(Abf + (size_t)MROWS_ * NCOL_);     // 1,241,088 f
  float* out   = (float*)d_out;

  hipLaunchKernelGGL(k_pool, dim3(TC_, B_), dim3(256), 0, stream,
                     enc, etype, eidv, midv, tbl, temb, iemb, partial);
  hipLaunchKernelGGL(k_entred, dim3(MROWS_), dim3(256), 0, stream,
                     partial, eswz);
  hipLaunchKernelGGL(k_gemm, dim3((NCOL_ + 127) / 128), dim3(256), 0, stream,
                     W, eswz, Abf);
  hipLaunchKernelGGL(k_score_z, dim3(B_ * D2_), dim3(64), 0, stream,
                     Abf, eswz, zbuf);
  hipLaunchKernelGGL(k_out, dim3(MROWS_), dim3(256), 0, stream,
                     zbuf, Rm, gam, bet, mu, var, out);
}

// Round 21
// 72.096 us; speedup vs baseline: 1.1454x; 1.1454x over previous
//
#include <hip/hip_runtime.h>
#include <hip/hip_bf16.h>

#define B_ 16
#define S_ 512
#define H_ 768
#define TS_ 20
#define IS_ 20
#define D_ 808
#define M_ 36
#define E_ 12
#define RNUM_ 97
#define D2_ 50
#define P_ (E_*E_)        // 144
#define NODES_ (M_+1)     // 37
#define NCOL_ (D2_*D_)    // 40400
#define MROWS_ (B_*E_)    // 192
#define KSTEPS_ 26
#define KPAD_ (KSTEPS_*32)  // 832
#define TC_ 8               // token chunks (64 tokens each)
#define BLKPAD_ 1040        // 1024B (4 k-rows x 64 cols fp32) + 16B pad
#define TILEB_ (8*BLKPAD_)  // 8320 B per K-step tile

typedef __attribute__((ext_vector_type(8))) short bf16x8;
typedef __attribute__((ext_vector_type(4))) float f32x4;

__device__ inline unsigned short f2bf(float f) {
  union { float f; unsigned u; } v; v.f = f;
  unsigned r = v.u + 0x7FFFu + ((v.u >> 16) & 1u);
  return (unsigned short)(r >> 16);
}

__device__ inline unsigned pack2bf(float a, float b) {
  union { __hip_bfloat162 h; unsigned u; } p;
  p.h = __float22bfloat162_rn(make_float2(a, b));
  return p.u;
}

__device__ inline void gll16(const float* src, void* lds) {
  __builtin_amdgcn_global_load_lds(
      (const __attribute__((address_space(1))) unsigned int*)src,
      (__attribute__((address_space(3))) unsigned int*)lds, 16, 0, 0);
}

// ---------------- kernel 1: token-parallel fused pooling (partials) ----------
__global__ __launch_bounds__(256) void k_pool(
    const float* __restrict__ enc, const int* __restrict__ etype,
    const int* __restrict__ eidv, const int* __restrict__ midv,
    const float* __restrict__ tbl, const float* __restrict__ temb,
    const float* __restrict__ iemb, float* __restrict__ partial) {
  int tc = blockIdx.x;
  int b  = blockIdx.y;
  int t  = threadIdx.x;
  __shared__ int midS[S_];
  __shared__ int cntS[NODES_];
  __shared__ int tyC[64], ivC[64];
  __shared__ float tblS[E_][NODES_];
  __shared__ float wtab[E_][40];
  __shared__ float wclsS[E_];
  __shared__ float invTS[E_];

  for (int i = t; i < NODES_; i += 256) cntS[i] = 0;
  __syncthreads();
  for (int s = t; s < S_; s += 256) {
    int m = midv[b * S_ + s];
    midS[s] = m;
    atomicAdd(&cntS[m], 1);
  }
  if (t < 64) {
    int s = tc * 64 + t;
    tyC[t] = etype[b * S_ + s];
    ivC[t] = eidv[b * S_ + s];
  }
  for (int i = t; i < E_ * NODES_; i += 256) {
    int e = i / NODES_, n = i % NODES_;
    tblS[e][n] = tbl[(size_t)(b * (E_ + 1) + (e + 1)) * NODES_ + n];
  }
  __syncthreads();
  if (t < E_) {
    float s = 0.f;
    for (int n = 0; n < NODES_; ++n) s += tblS[t][n];
    invTS[t] = (s > 0.f) ? 1.0f / s : 1.0f;
    wclsS[t] = tblS[t][0] * invTS[t];
  }
  __syncthreads();
  for (int i = t; i < E_ * NODES_; i += 256) {
    int e = i / NODES_, n = i % NODES_;
    wtab[e][n] = (n >= 1 && cntS[n] > 0)
                     ? tblS[e][n] * invTS[e] / (float)cntS[n] : 0.0f;
  }
  __syncthreads();

  const float* encB = enc + (size_t)(b * S_) * H_;
  if (t < 192) {
    f32x4 acc[E_];
    if (tc == 0) {
      float4 c = *(const float4*)(encB + 4 * t);
      #pragma unroll
      for (int e = 0; e < E_; ++e) {
        float w = wclsS[e];
        acc[e] = (f32x4){w * c.x, w * c.y, w * c.z, w * c.w};
      }
    } else {
      #pragma unroll
      for (int e = 0; e < E_; ++e) acc[e] = (f32x4){0.f, 0.f, 0.f, 0.f};
    }
    #pragma unroll 4
    for (int s = 0; s < 64; ++s) {
      int m = midS[tc * 64 + s];
      float4 v = *(const float4*)(encB + (size_t)(tc * 64 + s) * H_ + 4 * t);
      #pragma unroll
      for (int e = 0; e < E_; ++e) {
        float w = wtab[e][m];
        acc[e][0] += w * v.x;
        acc[e][1] += w * v.y;
        acc[e][2] += w * v.z;
        acc[e][3] += w * v.w;
      }
    }
    float* prow = partial + (size_t)(tc * MROWS_ + b * E_) * D_;
    #pragma unroll
    for (int e = 0; e < E_; ++e)
      *(f32x4*)(prow + (size_t)e * D_ + 4 * t) = acc[e];
  } else if (t - 192 < TS_ + IS_) {
    int tt = t - 192;
    float acc[E_];
    #pragma unroll
    for (int e = 0; e < E_; ++e) acc[e] = 0.f;
    for (int s = 0; s < 64; ++s) {
      int m = midS[tc * 64 + s];
      float val = (tt < TS_) ? temb[tyC[s] * TS_ + tt]
                             : iemb[ivC[s] * IS_ + (tt - TS_)];
      #pragma unroll
      for (int e = 0; e < E_; ++e) acc[e] += wtab[e][m] * val;
    }
    float* prow = partial + (size_t)(tc * MROWS_ + b * E_) * D_;
    #pragma unroll
    for (int e = 0; e < E_; ++e) prow[(size_t)e * D_ + H_ + tt] = acc[e];
  }
}

// ---------------- kernel 1b: reduce partials -> bf16 pre-swizzled eswz -------
__global__ __launch_bounds__(256) void k_entred(
    const float* __restrict__ partial, short* __restrict__ eswz) {
  int row = blockIdx.x;   // 0..191
  int t = threadIdx.x;
  for (int d = t; d < D_; d += 256) {
    float s = 0.f;
    #pragma unroll
    for (int tc = 0; tc < TC_; ++tc)
      s += partial[((size_t)tc * MROWS_ + row) * D_ + d];
    eswz[((size_t)(d >> 3) * MROWS_ + row) * 8 + (d & 7)] = (short)f2bf(s);
  }
  if (t < KPAD_ - D_) {
    int d = D_ + t;
    eswz[((size_t)(d >> 3) * MROWS_ + row) * 8 + (d & 7)] = 0;
  }
}

// ---------------- kernel 2: Abf[192,40400] = Ent @ Wview (8-wave blocks) -----
// BM=192 BN=64 BK=32, 512 threads (8 waves, 4x2 split: 48 rows x 32 cols).
// Same proven padded LDS layout (2-way banks = free) and 3-buf staging;
// STAGE = exactly 1 global_load_lds per thread. ~20 waves/CU occupancy.
__global__ __launch_bounds__(512) void k_gemm(
    const float* __restrict__ Wf, const short* __restrict__ eswz,
    short* __restrict__ Abf) {
  __shared__ __align__(16) char Bs[3 * TILEB_];   // 24.96 KiB
  const int tid = threadIdx.x;
  const int lane = tid & 63;
  const int ln15 = lane & 15;
  const int g = (lane >> 4) & 3;
  const int wv = tid >> 6;         // 0..7
  const int wr = wv >> 1;          // 0..3: row quarter (48 rows)
  const int wc = wv & 1;           // 0..1: col half (32 cols)
  const int colBase = blockIdx.x * 64;

  f32x4 acc[3][2];
  #pragma unroll
  for (int i = 0; i < 3; ++i)
    #pragma unroll
    for (int j = 0; j < 2; ++j)
      acc[i][j] = (f32x4){0.f, 0.f, 0.f, 0.f};

  // stage tile t: 8 blocks of 1024B (4 k-rows x 64 cols); 1 instr/thread
  auto STAGE = [&](int t, int bufi) {
    int kg = t * 32 + wv * 4 + (lane >> 4);    // block bi = wv
    if (kg > D_ - 1) kg = D_ - 1;              // tail killed by eswz zeros
    int cg = colBase + ln15 * 4;
    if (cg > NCOL_ - 4) cg = NCOL_ - 4;        // last block clamp
    gll16(Wf + (size_t)kg * NCOL_ + cg, Bs + bufi * TILEB_ + wv * BLKPAD_);
  };

  STAGE(0, 0);
  STAGE(1, 1);
  __syncthreads();

  int rb = 0;
  for (int t = 0; t < KSTEPS_; ++t) {
    int sb = rb + 2; if (sb >= 3) sb -= 3;
    if (t + 2 < KSTEPS_) STAGE(t + 2, sb);
    const char* bb = Bs + rb * TILEB_;
    // B fragments: 16 fp32 LDS reads (2-way banks = free), cvt to bf16
    bf16x8 bfr[2];
    #pragma unroll
    for (int nt = 0; nt < 2; ++nt) {
      float f[8];
      #pragma unroll
      for (int e = 0; e < 8; ++e) {
        int k = g * 8 + e;
        int col = wc * 32 + nt * 16 + ln15;
        f[e] = *(const float*)(bb + (k >> 2) * BLKPAD_ + (k & 3) * 256 + col * 4);
      }
      union { bf16x8 v; unsigned u[4]; } u;
      #pragma unroll
      for (int e2 = 0; e2 < 4; ++e2)
        u.u[e2] = pack2bf(f[2 * e2], f[2 * e2 + 1]);
      bfr[nt] = u.v;
    }
    // A fragments: 3 x dwordx4 from eswz (L2-resident)
    bf16x8 af[3];
    #pragma unroll
    for (int mt = 0; mt < 3; ++mt)
      af[mt] = *(const bf16x8*)&eswz[
          ((size_t)(t * 4 + g) * MROWS_ + wr * 48 + mt * 16 + ln15) * 8];
    #pragma unroll
    for (int mt = 0; mt < 3; ++mt)
      #pragma unroll
      for (int nt = 0; nt < 2; ++nt)
        acc[mt][nt] = __builtin_amdgcn_mfma_f32_16x16x32_bf16(
            af[mt], bfr[nt], acc[mt][nt], 0, 0, 0);
    __syncthreads();
    rb = (rb == 2) ? 0 : rb + 1;
  }

  // epilogue: C/D layout col = lane&15, row = g*4 + j; store bf16
  #pragma unroll
  for (int mt = 0; mt < 3; ++mt) {
    int row = wr * 48 + mt * 16 + g * 4;
    #pragma unroll
    for (int nt = 0; nt < 2; ++nt) {
      int col = colBase + wc * 32 + nt * 16 + ln15;
      if (col < NCOL_) {
        #pragma unroll
        for (int j = 0; j < 4; ++j)
          Abf[(size_t)(row + j) * NCOL_ + col] = (short)f2bf(acc[mt][nt][j]);
      }
    }
  }
}

// ---------------- kernel 3: z via MFMA — one wave per (b, r) ---------------
__global__ __launch_bounds__(64) void k_score_z(
    const short* __restrict__ Abf, const short* __restrict__ eswz,
    float* __restrict__ zbuf) {
  int w = blockIdx.x;            // 0..799
  int b = w / D2_;
  int r = w % D2_;
  int lane = threadIdx.x;
  int ln15 = lane & 15;
  int g = lane >> 4;
  int m = b * E_ + ln15;
  if (m > MROWS_ - 1) m = MROWS_ - 1;
  const short* ab = Abf + (size_t)m * NCOL_ + (size_t)r * D_ + g * 8;
  const short* bb = eswz + ((size_t)g * MROWS_ + m) * 8;
  f32x4 acc = (f32x4){0.f, 0.f, 0.f, 0.f};
  #pragma unroll
  for (int t = 0; t < KSTEPS_; ++t) {
    bf16x8 af = *(const bf16x8*)(ab + t * 32);
    bf16x8 bf = *(const bf16x8*)(bb + (size_t)t * 4 * MROWS_ * 8);
    acc = __builtin_amdgcn_mfma_f32_16x16x32_bf16(af, bf, acc, 0, 0, 0);
  }
  if (ln15 < E_ && g < 3) {
    #pragma unroll
    for (int jj = 0; jj < 4; ++jj)
      zbuf[(size_t)(b * E_ + g * 4 + jj) * (D2_ * E_) + r * E_ + ln15] = acc[jj];
  }
}

// ---------------- kernel 4: BN + R projection ------------------------------
__global__ __launch_bounds__(256) void k_out(
    const float* __restrict__ zbuf, const float* __restrict__ Rm,
    const float* __restrict__ gam, const float* __restrict__ bet,
    const float* __restrict__ mu, const float* __restrict__ var,
    float* __restrict__ out) {
  int blk = blockIdx.x;   // b*12+ke
  int t = threadIdx.x;
  __shared__ float zS[D2_ * E_];       // 600
  __shared__ float Rs[RNUM_ * D2_];    // 4850
  for (int i = t; i < D2_ * E_; i += 256) {
    int r = i / E_;
    float z = zbuf[(size_t)blk * (D2_ * E_) + i];
    zS[i] = (z - mu[r]) * rsqrtf(var[r] + 1e-5f) * gam[r] + bet[r];
  }
  for (int i = t; i < RNUM_ * D2_; i += 256) Rs[i] = Rm[i];
  __syncthreads();
  for (int o = t; o < E_ * RNUM_; o += 256) {
    int je = o / RNUM_;
    int k = o % RNUM_;
    float s = 0.f;
    #pragma unroll
    for (int r = 0; r < D2_; ++r) s += zS[r * E_ + je] * Rs[k * D2_ + r];
    out[(size_t)blk * (E_ * RNUM_) + o] = s;
  }
}

extern "C" void kernel_launch(void* const* d_in, const int* in_sizes, int n_in,
                              void* d_out, int out_size, void* d_ws, size_t ws_size,
                              hipStream_t stream) {
  const float* enc  = (const float*)d_in[0];
  const int*  etype = (const int*)d_in[1];
  const int*  eidv  = (const int*)d_in[2];
  const int*  midv  = (const int*)d_in[3];
  const float* tbl  = (const float*)d_in[4];
  const float* temb = (const float*)d_in[5];
  const float* iemb = (const float*)d_in[6];
  const float* W    = (const float*)d_in[7];
  const float* Rm   = (const float*)d_in[8];
  const float* gam  = (const float*)d_in[9];
  const float* bet  = (const float*)d_in[10];
  const float* mu   = (const float*)d_in[11];
  const float* var  = (const float*)d_in[12];

  // ws layout: zbuf | eswz | Abf | partial
  float* ws    = (float*)d_ws;
  float* zbuf  = ws;                                           // 115,200 f
  short* eswz  = (short*)(zbuf + (size_t)MROWS_ * D2_ * E_);   // 159,744 sh
  short* Abf   = eswz + (size_t)104 * MROWS_ * 8;              // 7,756,800 sh
  float* partial = (float*)(Abf + (size_t)MROWS_ * NCOL_);     // 1,241,088 f
  float* out   = (float*)d_out;

  hipLaunchKernelGGL(k_pool, dim3(TC_, B_), dim3(256), 0, stream,
                     enc, etype, eidv, midv, tbl, temb, iemb, partial);
  hipLaunchKernelGGL(k_entred, dim3(MROWS_), dim3(256), 0, stream,
                     partial, eswz);
  hipLaunchKernelGGL(k_gemm, dim3((NCOL_ + 63) / 64), dim3(512), 0, stream,
                     W, eswz, Abf);
  hipLaunchKernelGGL(k_score_z, dim3(B_ * D2_), dim3(64), 0, stream,
                     Abf, eswz, zbuf);
  hipLaunchKernelGGL(k_out, dim3(MROWS_), dim3(256), 0, stream,
                     zbuf, Rm, gam, bet, mu, var, out);
}

// Round 22
// 70.167 us; speedup vs baseline: 1.1769x; 1.0275x over previous
//
#include <hip/hip_runtime.h>
#include <hip/hip_bf16.h>

#define B_ 16
#define S_ 512
#define H_ 768
#define TS_ 20
#define IS_ 20
#define D_ 808
#define M_ 36
#define E_ 12
#define RNUM_ 97
#define D2_ 50
#define P_ (E_*E_)        // 144
#define NODES_ (M_+1)     // 37
#define NCOL_ (D2_*D_)    // 40400
#define MROWS_ (B_*E_)    // 192
#define KSTEPS_ 26
#define KPAD_ (KSTEPS_*32)  // 832
#define TC_ 8               // token chunks (64 tokens each)
#define BLKPAD_ 1040        // 1024B (4 k-rows x 64 cols fp32) + 16B pad
#define TILEB_ (8*BLKPAD_)  // 8320 B per K-step tile
#define GTILES_ 632         // gemm column tiles = 8 XCDs * 79

typedef __attribute__((ext_vector_type(8))) short bf16x8;
typedef __attribute__((ext_vector_type(4))) float f32x4;

__device__ inline unsigned short f2bf(float f) {
  union { float f; unsigned u; } v; v.f = f;
  unsigned r = v.u + 0x7FFFu + ((v.u >> 16) & 1u);
  return (unsigned short)(r >> 16);
}

__device__ inline unsigned pack2bf(float a, float b) {
  union { __hip_bfloat162 h; unsigned u; } p;
  p.h = __float22bfloat162_rn(make_float2(a, b));
  return p.u;
}

__device__ inline void gll16(const float* src, void* lds) {
  __builtin_amdgcn_global_load_lds(
      (const __attribute__((address_space(1))) unsigned int*)src,
      (__attribute__((address_space(3))) unsigned int*)lds, 16, 0, 0);
}

// ---------------- kernel 1: token-parallel fused pooling (partials) ----------
__global__ __launch_bounds__(256) void k_pool(
    const float* __restrict__ enc, const int* __restrict__ etype,
    const int* __restrict__ eidv, const int* __restrict__ midv,
    const float* __restrict__ tbl, const float* __restrict__ temb,
    const float* __restrict__ iemb, float* __restrict__ partial) {
  int tc = blockIdx.x;
  int b  = blockIdx.y;
  int t  = threadIdx.x;
  __shared__ int midS[S_];
  __shared__ int cntS[NODES_];
  __shared__ int tyC[64], ivC[64];
  __shared__ float tblS[E_][NODES_];
  __shared__ float wtab[E_][40];
  __shared__ float wclsS[E_];
  __shared__ float invTS[E_];

  for (int i = t; i < NODES_; i += 256) cntS[i] = 0;
  __syncthreads();
  for (int s = t; s < S_; s += 256) {
    int m = midv[b * S_ + s];
    midS[s] = m;
    atomicAdd(&cntS[m], 1);
  }
  if (t < 64) {
    int s = tc * 64 + t;
    tyC[t] = etype[b * S_ + s];
    ivC[t] = eidv[b * S_ + s];
  }
  for (int i = t; i < E_ * NODES_; i += 256) {
    int e = i / NODES_, n = i % NODES_;
    tblS[e][n] = tbl[(size_t)(b * (E_ + 1) + (e + 1)) * NODES_ + n];
  }
  __syncthreads();
  if (t < E_) {
    float s = 0.f;
    for (int n = 0; n < NODES_; ++n) s += tblS[t][n];
    invTS[t] = (s > 0.f) ? 1.0f / s : 1.0f;
    wclsS[t] = tblS[t][0] * invTS[t];
  }
  __syncthreads();
  for (int i = t; i < E_ * NODES_; i += 256) {
    int e = i / NODES_, n = i % NODES_;
    wtab[e][n] = (n >= 1 && cntS[n] > 0)
                     ? tblS[e][n] * invTS[e] / (float)cntS[n] : 0.0f;
  }
  __syncthreads();

  const float* encB = enc + (size_t)(b * S_) * H_;
  if (t < 192) {
    f32x4 acc[E_];
    if (tc == 0) {
      float4 c = *(const float4*)(encB + 4 * t);
      #pragma unroll
      for (int e = 0; e < E_; ++e) {
        float w = wclsS[e];
        acc[e] = (f32x4){w * c.x, w * c.y, w * c.z, w * c.w};
      }
    } else {
      #pragma unroll
      for (int e = 0; e < E_; ++e) acc[e] = (f32x4){0.f, 0.f, 0.f, 0.f};
    }
    #pragma unroll 4
    for (int s = 0; s < 64; ++s) {
      int m = midS[tc * 64 + s];
      float4 v = *(const float4*)(encB + (size_t)(tc * 64 + s) * H_ + 4 * t);
      #pragma unroll
      for (int e = 0; e < E_; ++e) {
        float w = wtab[e][m];
        acc[e][0] += w * v.x;
        acc[e][1] += w * v.y;
        acc[e][2] += w * v.z;
        acc[e][3] += w * v.w;
      }
    }
    float* prow = partial + (size_t)(tc * MROWS_ + b * E_) * D_;
    #pragma unroll
    for (int e = 0; e < E_; ++e)
      *(f32x4*)(prow + (size_t)e * D_ + 4 * t) = acc[e];
  } else if (t - 192 < TS_ + IS_) {
    int tt = t - 192;
    float acc[E_];
    #pragma unroll
    for (int e = 0; e < E_; ++e) acc[e] = 0.f;
    for (int s = 0; s < 64; ++s) {
      int m = midS[tc * 64 + s];
      float val = (tt < TS_) ? temb[tyC[s] * TS_ + tt]
                             : iemb[ivC[s] * IS_ + (tt - TS_)];
      #pragma unroll
      for (int e = 0; e < E_; ++e) acc[e] += wtab[e][m] * val;
    }
    float* prow = partial + (size_t)(tc * MROWS_ + b * E_) * D_;
    #pragma unroll
    for (int e = 0; e < E_; ++e) prow[(size_t)e * D_ + H_ + tt] = acc[e];
  }
}

// ---------------- kernel 1b: reduce partials -> bf16 pre-swizzled eswz -------
__global__ __launch_bounds__(256) void k_entred(
    const float* __restrict__ partial, short* __restrict__ eswz) {
  int row = blockIdx.x;   // 0..191
  int t = threadIdx.x;
  for (int d = t; d < D_; d += 256) {
    float s = 0.f;
    #pragma unroll
    for (int tc = 0; tc < TC_; ++tc)
      s += partial[((size_t)tc * MROWS_ + row) * D_ + d];
    eswz[((size_t)(d >> 3) * MROWS_ + row) * 8 + (d & 7)] = (short)f2bf(s);
  }
  if (t < KPAD_ - D_) {
    int d = D_ + t;
    eswz[((size_t)(d >> 3) * MROWS_ + row) * 8 + (d & 7)] = 0;
  }
}

// ---------------- kernel 2: Abf[192,40400] = Ent @ Wview (8-wave + XCD swz) --
// BM=192 BN=64 BK=32, 512 threads (8 waves, 4x2 split: 48 rows x 32 cols).
// T1 XCD-aware tile swizzle: 632 tiles = 8 XCDs x 79 -> XCD x owns the
// contiguous tile range [79x, 79x+79) so its L2 sees contiguous W demand.
__global__ __launch_bounds__(512) void k_gemm(
    const float* __restrict__ Wf, const short* __restrict__ eswz,
    short* __restrict__ Abf) {
  __shared__ __align__(16) char Bs[3 * TILEB_];   // 24.96 KiB
  const int tid = threadIdx.x;
  const int lane = tid & 63;
  const int ln15 = lane & 15;
  const int g = (lane >> 4) & 3;
  const int wv = tid >> 6;         // 0..7
  const int wr = wv >> 1;          // 0..3: row quarter (48 rows)
  const int wc = wv & 1;           // 0..1: col half (32 cols)
  const int bid = blockIdx.x;
  const int tile = (bid & 7) * (GTILES_ / 8) + (bid >> 3);   // bijective
  const int colBase = tile * 64;

  f32x4 acc[3][2];
  #pragma unroll
  for (int i = 0; i < 3; ++i)
    #pragma unroll
    for (int j = 0; j < 2; ++j)
      acc[i][j] = (f32x4){0.f, 0.f, 0.f, 0.f};

  auto STAGE = [&](int t, int bufi) {
    int kg = t * 32 + wv * 4 + (lane >> 4);    // block bi = wv
    if (kg > D_ - 1) kg = D_ - 1;              // tail killed by eswz zeros
    int cg = colBase + ln15 * 4;
    if (cg > NCOL_ - 4) cg = NCOL_ - 4;        // last block clamp
    gll16(Wf + (size_t)kg * NCOL_ + cg, Bs + bufi * TILEB_ + wv * BLKPAD_);
  };

  STAGE(0, 0);
  STAGE(1, 1);
  __syncthreads();

  int rb = 0;
  for (int t = 0; t < KSTEPS_; ++t) {
    int sb = rb + 2; if (sb >= 3) sb -= 3;
    if (t + 2 < KSTEPS_) STAGE(t + 2, sb);
    const char* bb = Bs + rb * TILEB_;
    bf16x8 bfr[2];
    #pragma unroll
    for (int nt = 0; nt < 2; ++nt) {
      float f[8];
      #pragma unroll
      for (int e = 0; e < 8; ++e) {
        int k = g * 8 + e;
        int col = wc * 32 + nt * 16 + ln15;
        f[e] = *(const float*)(bb + (k >> 2) * BLKPAD_ + (k & 3) * 256 + col * 4);
      }
      union { bf16x8 v; unsigned u[4]; } u;
      #pragma unroll
      for (int e2 = 0; e2 < 4; ++e2)
        u.u[e2] = pack2bf(f[2 * e2], f[2 * e2 + 1]);
      bfr[nt] = u.v;
    }
    bf16x8 af[3];
    #pragma unroll
    for (int mt = 0; mt < 3; ++mt)
      af[mt] = *(const bf16x8*)&eswz[
          ((size_t)(t * 4 + g) * MROWS_ + wr * 48 + mt * 16 + ln15) * 8];
    #pragma unroll
    for (int mt = 0; mt < 3; ++mt)
      #pragma unroll
      for (int nt = 0; nt < 2; ++nt)
        acc[mt][nt] = __builtin_amdgcn_mfma_f32_16x16x32_bf16(
            af[mt], bfr[nt], acc[mt][nt], 0, 0, 0);
    __syncthreads();
    rb = (rb == 2) ? 0 : rb + 1;
  }

  // epilogue: C/D layout col = lane&15, row = g*4 + j; store bf16
  #pragma unroll
  for (int mt = 0; mt < 3; ++mt) {
    int row = wr * 48 + mt * 16 + g * 4;
    #pragma unroll
    for (int nt = 0; nt < 2; ++nt) {
      int col = colBase + wc * 32 + nt * 16 + ln15;
      if (col < NCOL_) {
        #pragma unroll
        for (int j = 0; j < 4; ++j)
          Abf[(size_t)(row + j) * NCOL_ + col] = (short)f2bf(acc[mt][nt][j]);
      }
    }
  }
}

// ---------------- kernel 3: z via MFMA — one wave per (b, r) ---------------
__global__ __launch_bounds__(64) void k_score_z(
    const short* __restrict__ Abf, const short* __restrict__ eswz,
    float* __restrict__ zbuf) {
  int w = blockIdx.x;            // 0..799
  int b = w / D2_;
  int r = w % D2_;
  int lane = threadIdx.x;
  int ln15 = lane & 15;
  int g = lane >> 4;
  int m = b * E_ + ln15;
  if (m > MROWS_ - 1) m = MROWS_ - 1;
  const short* ab = Abf + (size_t)m * NCOL_ + (size_t)r * D_ + g * 8;
  const short* bb = eswz + ((size_t)g * MROWS_ + m) * 8;
  f32x4 acc = (f32x4){0.f, 0.f, 0.f, 0.f};
  #pragma unroll
  for (int t = 0; t < KSTEPS_; ++t) {
    bf16x8 af = *(const bf16x8*)(ab + t * 32);
    bf16x8 bf = *(const bf16x8*)(bb + (size_t)t * 4 * MROWS_ * 8);
    acc = __builtin_amdgcn_mfma_f32_16x16x32_bf16(af, bf, acc, 0, 0, 0);
  }
  if (ln15 < E_ && g < 3) {
    #pragma unroll
    for (int jj = 0; jj < 4; ++jj)
      zbuf[(size_t)(b * E_ + g * 4 + jj) * (D2_ * E_) + r * E_ + ln15] = acc[jj];
  }
}

// ---------------- kernel 4: BN + R projection ------------------------------
__global__ __launch_bounds__(256) void k_out(
    const float* __restrict__ zbuf, const float* __restrict__ Rm,
    const float* __restrict__ gam, const float* __restrict__ bet,
    const float* __restrict__ mu, const float* __restrict__ var,
    float* __restrict__ out) {
  int blk = blockIdx.x;   // b*12+ke
  int t = threadIdx.x;
  __shared__ float zS[D2_ * E_];       // 600
  __shared__ float Rs[RNUM_ * D2_];    // 4850
  for (int i = t; i < D2_ * E_; i += 256) {
    int r = i / E_;
    float z = zbuf[(size_t)blk * (D2_ * E_) + i];
    zS[i] = (z - mu[r]) * rsqrtf(var[r] + 1e-5f) * gam[r] + bet[r];
  }
  for (int i = t; i < RNUM_ * D2_; i += 256) Rs[i] = Rm[i];
  __syncthreads();
  for (int o = t; o < E_ * RNUM_; o += 256) {
    int je = o / RNUM_;
    int k = o % RNUM_;
    float s = 0.f;
    #pragma unroll
    for (int r = 0; r < D2_; ++r) s += zS[r * E_ + je] * Rs[k * D2_ + r];
    out[(size_t)blk * (E_ * RNUM_) + o] = s;
  }
}

extern "C" void kernel_launch(void* const* d_in, const int* in_sizes, int n_in,
                              void* d_out, int out_size, void* d_ws, size_t ws_size,
                              hipStream_t stream) {
  const float* enc  = (const float*)d_in[0];
  const int*  etype = (const int*)d_in[1];
  const int*  eidv  = (const int*)d_in[2];
  const int*  midv  = (const int*)d_in[3];
  const float* tbl  = (const float*)d_in[4];
  const float* temb = (const float*)d_in[5];
  const float* iemb = (const float*)d_in[6];
  const float* W    = (const float*)d_in[7];
  const float* Rm   = (const float*)d_in[8];
  const float* gam  = (const float*)d_in[9];
  const float* bet  = (const float*)d_in[10];
  const float* mu   = (const float*)d_in[11];
  const float* var  = (const float*)d_in[12];

  // ws layout: zbuf | eswz | Abf | partial
  float* ws    = (float*)d_ws;
  float* zbuf  = ws;                                           // 115,200 f
  short* eswz  = (short*)(zbuf + (size_t)MROWS_ * D2_ * E_);   // 159,744 sh
  short* Abf   = eswz + (size_t)104 * MROWS_ * 8;              // 7,756,800 sh
  float* partial = (float*)(Abf + (size_t)MROWS_ * NCOL_);     // 1,241,088 f
  float* out   = (float*)d_out;

  hipLaunchKernelGGL(k_pool, dim3(TC_, B_), dim3(256), 0, stream,
                     enc, etype, eidv, midv, tbl, temb, iemb, partial);
  hipLaunchKernelGGL(k_entred, dim3(MROWS_), dim3(256), 0, stream,
                     partial, eswz);
  hipLaunchKernelGGL(k_gemm, dim3(GTILES_), dim3(512), 0, stream,
                     W, eswz, Abf);
  hipLaunchKernelGGL(k_score_z, dim3(B_ * D2_), dim3(64), 0, stream,
                     Abf, eswz, zbuf);
  hipLaunchKernelGGL(k_out, dim3(MROWS_), dim3(256), 0, stream,
                     zbuf, Rm, gam, bet, mu, var, out);
}